// Round 1
// baseline (6401.399 us; speedup 1.0000x reference)
//
#include <hip/hip_runtime.h>

typedef __bf16 bf16;
typedef __attribute__((ext_vector_type(8))) __bf16 bf16x8;
typedef __attribute__((ext_vector_type(4))) float f32x4;

// XOR swizzle: spread rows-8-apart across banks (row stride ≡ 0 mod 32 banks
// otherwise). Flips col bits [2:4]; preserves 4-float (16B) alignment.
__device__ __forceinline__ int swz(int r, int c) {
  return c ^ (((r >> 3) & 7) << 2);
}

// ---------------------------------------------------------------------------
// GEMM: out[M][1024](OUT) = A[M][1024](f32) @ W[1024][1024](f32) + bias(f32)
// (+ seg_emb gather if mode==1). Pure f32 VALU core: 16x16 threads, each an
// 8x8 micro-tile of a 128x128 block tile. f32 LDS staging (exact vs ref).
// UNCHANGED from verified version.
// ---------------------------------------------------------------------------
template <typename OUT>
__global__ __launch_bounds__(256, 2) void gemm_f32(
    const float* __restrict__ A, const float* __restrict__ W,
    const float* __restrict__ bias, OUT* __restrict__ out, int M, int mode,
    const int* __restrict__ segids, const float* __restrict__ segemb) {
  __shared__ __align__(16) float As[128][36];
  __shared__ __align__(16) float Bs[32][132];

  int tid = threadIdx.x;
  int tx = tid & 15, ty = tid >> 4;
  int nTilesM = M >> 7;
  int bm = blockIdx.x % nTilesM, bn = blockIdx.x / nTilesM;
  int m0 = bm * 128, n0 = bn * 128;

  float acc[8][8];
#pragma unroll
  for (int i = 0; i < 8; i++)
#pragma unroll
    for (int j = 0; j < 8; j++) acc[i][j] = 0.f;

  for (int k0 = 0; k0 < 1024; k0 += 32) {
#pragma unroll
    for (int u = tid; u < 512; u += 256) {
      int r = u >> 2, c = (u & 3) * 8;
      const float* src = A + (size_t)(m0 + r) * 1024 + k0 + c;
      *(f32x4*)&As[r][c] = *(const f32x4*)src;
      *(f32x4*)&As[r][c + 4] = *(const f32x4*)(src + 4);
    }
#pragma unroll
    for (int u = tid; u < 512; u += 256) {
      int r = u >> 4, cc = (u & 15) * 8;
      const float* src = W + (size_t)(k0 + r) * 1024 + n0 + cc;
      *(f32x4*)&Bs[r][cc] = *(const f32x4*)src;
      *(f32x4*)&Bs[r][cc + 4] = *(const f32x4*)(src + 4);
    }
    __syncthreads();
#pragma unroll
    for (int kk = 0; kk < 32; kk++) {
      float av[8], bv[8];
#pragma unroll
      for (int i = 0; i < 8; i++) av[i] = As[ty * 8 + i][kk];
#pragma unroll
      for (int j = 0; j < 8; j++) bv[j] = Bs[kk][tx * 8 + j];
#pragma unroll
      for (int i = 0; i < 8; i++)
#pragma unroll
        for (int j = 0; j < 8; j++) acc[i][j] += av[i] * bv[j];
    }
    __syncthreads();
  }

#pragma unroll
  for (int i = 0; i < 8; i++) {
    int m = m0 + ty * 8 + i;
    int seg = (mode == 1) ? segids[m] : 0;
#pragma unroll
    for (int j = 0; j < 8; j++) {
      int n = n0 + tx * 8 + j;
      float v = acc[i][j] + bias[n];
      if (mode == 1) v += segemb[(size_t)seg * 1024 + n];
      out[(size_t)m * 1024 + n] = (OUT)v;
    }
  }
}

// ---------------------------------------------------------------------------
// Scores: Sc[bh*512+t][4096] = mask ? (Q[b,t,h*64:] . K[b,s,h*64:]) * 0.125
//                                   : -1e9
// NT-GEMM, K=64 single pass. Tile 128t x 128s; thread = 8x8 micro-tile.
// Q/K staged in LDS with XOR-swizzled columns (unswizzled layout is a
// 16-way bank conflict on the K-fragment read: rows 8 apart, stride 68).
// ---------------------------------------------------------------------------
__global__ __launch_bounds__(256, 2) void qk_scores(
    const float* __restrict__ Qp, const float* __restrict__ Kp,
    const int* __restrict__ mask, float* __restrict__ Sc) {
  __shared__ __align__(16) float Qs[128][68];
  __shared__ __align__(16) float Ks[128][68];

  int tid = threadIdx.x;
  int tx = tid & 15, ty = tid >> 4;
  int bid = blockIdx.x;
  int bh = bid >> 7;  // b*16+h, 0..63
  int rest = bid & 127;
  int tm = rest & 3, sn = rest >> 2;  // 4 t-tiles x 32 s-tiles
  int b = bh >> 4, h = bh & 15;
  int t0 = tm << 7, s0 = sn << 7;

  // stage Q[128][64] and K[128][64] (h-slice), swizzled
#pragma unroll
  for (int u = tid; u < 512; u += 256) {
    int r = u >> 2, c = (u & 3) << 4;
    const float* qsrc = Qp + (((size_t)((b << 9) + t0 + r)) << 10) + (h << 6) + c;
    const float* ksrc = Kp + (((size_t)((b << 12) + s0 + r)) << 10) + (h << 6) + c;
#pragma unroll
    for (int q4 = 0; q4 < 4; ++q4) {
      *(f32x4*)&Qs[r][swz(r, c + q4 * 4)] = *(const f32x4*)(qsrc + q4 * 4);
      *(f32x4*)&Ks[r][swz(r, c + q4 * 4)] = *(const f32x4*)(ksrc + q4 * 4);
    }
  }
  __syncthreads();

  float acc[8][8];
#pragma unroll
  for (int i = 0; i < 8; i++)
#pragma unroll
    for (int j = 0; j < 8; j++) acc[i][j] = 0.f;

  // r>>3 == ty for all av rows (r = ty*8+i, i<8), so one XOR per kk per operand
#pragma unroll 8
  for (int kk = 0; kk < 64; ++kk) {
    int kq = kk ^ ((ty & 7) << 2);
    int kx = kk ^ ((tx & 7) << 2);
    float av[8], bv[8];
#pragma unroll
    for (int i = 0; i < 8; i++) av[i] = Qs[ty * 8 + i][kq];
#pragma unroll
    for (int j = 0; j < 8; j++) bv[j] = Ks[tx * 8 + j][kx];
#pragma unroll
    for (int i = 0; i < 8; i++)
#pragma unroll
      for (int j = 0; j < 8; j++) acc[i][j] += av[i] * bv[j];
  }

  const int* mrow = mask + (b << 12) + s0 + tx * 8;
  bool mk[8];
#pragma unroll
  for (int j = 0; j < 8; j++) mk[j] = (mrow[j] != 0);

#pragma unroll
  for (int i = 0; i < 8; i++) {
    size_t row = (((size_t)((bh << 9) + t0 + ty * 8 + i)) << 12) + s0 + tx * 8;
    f32x4 v0, v1;
#pragma unroll
    for (int j = 0; j < 4; j++) {
      v0[j] = mk[j] ? acc[i][j] * 0.125f : -1.0e9f;
      v1[j] = mk[4 + j] ? acc[i][4 + j] * 0.125f : -1.0e9f;
    }
    *(f32x4*)&Sc[row] = v0;
    *(f32x4*)&Sc[row + 4] = v1;
  }
}

// ---------------------------------------------------------------------------
// Softmax (exact, same arithmetic as verified kernel) + provenance.
// Block per (b,t); loops h; normalizes Sc IN PLACE; pacc accumulated in LDS
// across h (same-thread stripes, no atomics). Wave-shuffle reductions.
// ---------------------------------------------------------------------------
__global__ __launch_bounds__(256) void softmax_prov(
    float* __restrict__ Sc, float* __restrict__ prov) {
  __shared__ __align__(16) float rowb[4096];
  __shared__ __align__(16) float pacc[4096];
  __shared__ float red[4];

  int tid = threadIdx.x, wv = tid >> 6;
  int bt = blockIdx.x, b = bt >> 9, t = bt & 511;

#pragma unroll
  for (int it = 0; it < 4; ++it) {
    int s = (tid << 2) + (it << 10);
    rowb[s] = 0.f;  // touch to keep layout; not required
    pacc[s] = 0.f; pacc[s + 1] = 0.f; pacc[s + 2] = 0.f; pacc[s + 3] = 0.f;
  }

  for (int h = 0; h < 16; ++h) {
    size_t base = ((size_t)(((b * 16 + h) << 9) + t)) << 12;
    float mx = -3.0e38f;
#pragma unroll
    for (int it = 0; it < 4; ++it) {
      int s = (tid << 2) + (it << 10);
      f32x4 v = *(const f32x4*)&Sc[base + s];
      *(f32x4*)&rowb[s] = v;
      mx = fmaxf(fmaxf(fmaxf(mx, v[0]), v[1]), fmaxf(v[2], v[3]));
    }
#pragma unroll
    for (int o = 32; o; o >>= 1) mx = fmaxf(mx, __shfl_xor(mx, o));
    if ((tid & 63) == 0) red[wv] = mx;
    __syncthreads();
    float m = fmaxf(fmaxf(red[0], red[1]), fmaxf(red[2], red[3]));

    float sm = 0.f;
#pragma unroll
    for (int it = 0; it < 4; ++it) {
      int s = (tid << 2) + (it << 10);
      f32x4 v = *(const f32x4*)&rowb[s];
      f32x4 p;
      p[0] = __expf(v[0] - m);
      p[1] = __expf(v[1] - m);
      p[2] = __expf(v[2] - m);
      p[3] = __expf(v[3] - m);
      *(f32x4*)&rowb[s] = p;
      sm += (p[0] + p[1]) + (p[2] + p[3]);
    }
#pragma unroll
    for (int o = 32; o; o >>= 1) sm += __shfl_xor(sm, o);
    __syncthreads();  // all reads of red (for m) done before overwrite
    if ((tid & 63) == 0) red[wv] = sm;
    __syncthreads();
    float il = 1.0f / (((red[0] + red[1]) + (red[2] + red[3])));

#pragma unroll
    for (int it = 0; it < 4; ++it) {
      int s = (tid << 2) + (it << 10);
      f32x4 p = *(const f32x4*)&rowb[s];
      f32x4 pn;
      pn[0] = p[0] * il; pn[1] = p[1] * il;
      pn[2] = p[2] * il; pn[3] = p[3] * il;
      *(f32x4*)&Sc[base + s] = pn;
      f32x4 pa = *(const f32x4*)&pacc[s];
      pa[0] += pn[0] * 0.0625f; pa[1] += pn[1] * 0.0625f;
      pa[2] += pn[2] * 0.0625f; pa[3] += pn[3] * 0.0625f;
      *(f32x4*)&pacc[s] = pa;
    }
    __syncthreads();  // il reads done before next h overwrites red
  }

#pragma unroll
  for (int it = 0; it < 4; ++it) {
    int s = (tid << 2) + (it << 10);
    *(f32x4*)&prov[(((size_t)((b << 9) + t)) << 12) + s] = *(const f32x4*)&pacc[s];
  }
}

// ---------------------------------------------------------------------------
// PV: Oat[b,t,h*64+d] = sum_s P[bh*512+t][s] * V[b,s,h*64+d].
// Per (b,h): M=512, N=64, K=4096. Tile 128t x 64d; thread = 8x4.
// P staged swizzled (rows 8 apart share banks otherwise); V rows are fine.
// ---------------------------------------------------------------------------
__global__ __launch_bounds__(256, 2) void pv_gemm(
    const float* __restrict__ P, const float* __restrict__ Vp,
    float* __restrict__ Oat) {
  __shared__ __align__(16) float Ps[128][36];
  __shared__ __align__(16) float Vs[32][68];

  int tid = threadIdx.x, tx = tid & 15, ty = tid >> 4;
  int bid = blockIdx.x;
  int bh = bid >> 2, tm = bid & 3;
  int b = bh >> 4, h = bh & 15;
  int t0 = tm << 7;

  float acc[8][4];
#pragma unroll
  for (int i = 0; i < 8; i++)
#pragma unroll
    for (int j = 0; j < 4; j++) acc[i][j] = 0.f;

  for (int k0 = 0; k0 < 4096; k0 += 32) {
#pragma unroll
    for (int u = tid; u < 512; u += 256) {
      int r = u >> 2, c = (u & 3) << 3;
      const float* src = P + (((size_t)((bh << 9) + t0 + r)) << 12) + k0 + c;
      *(f32x4*)&Ps[r][swz(r, c)] = *(const f32x4*)src;
      *(f32x4*)&Ps[r][swz(r, c + 4)] = *(const f32x4*)(src + 4);
    }
    {
      int r = tid >> 3, c = (tid & 7) << 3;
      const float* src = Vp + (((size_t)((b << 12) + k0 + r)) << 10) + (h << 6) + c;
      *(f32x4*)&Vs[r][c] = *(const f32x4*)src;
      *(f32x4*)&Vs[r][c + 4] = *(const f32x4*)(src + 4);
    }
    __syncthreads();
#pragma unroll
    for (int kk = 0; kk < 32; ++kk) {
      int kq = kk ^ ((ty & 7) << 2);
      float av[8], bv[4];
#pragma unroll
      for (int i = 0; i < 8; i++) av[i] = Ps[ty * 8 + i][kq];
#pragma unroll
      for (int j = 0; j < 4; j++) bv[j] = Vs[kk][tx * 4 + j];
#pragma unroll
      for (int i = 0; i < 8; i++)
#pragma unroll
        for (int j = 0; j < 4; j++) acc[i][j] += av[i] * bv[j];
    }
    __syncthreads();
  }

#pragma unroll
  for (int i = 0; i < 8; i++) {
    f32x4 v;
#pragma unroll
    for (int j = 0; j < 4; j++) v[j] = acc[i][j];
    *(f32x4*)&Oat[(((size_t)((b << 9) + t0 + ty * 8 + i)) << 10) + (h << 6) +
                  (tx << 2)] = v;
  }
}

// ---------------------------------------------------------------------------
// Fallback: previous verified naive attention (used if ws too small).
// ---------------------------------------------------------------------------
__global__ __launch_bounds__(256) void attn_naive(
    const float* __restrict__ Qp, const float* __restrict__ Kp,
    const bf16* __restrict__ Vp, const int* __restrict__ mask,
    float* __restrict__ Oatt, float* __restrict__ prov) {
  int bt = blockIdx.x;
  int b = bt >> 9, t = bt & 511;
  __shared__ float qs[64];
  __shared__ float sc[4096];
  __shared__ float pacc[4096];
  __shared__ float red[256];
  __shared__ float po[4][64];
  int tid = threadIdx.x, wv = tid >> 6, lane = tid & 63;

  for (int s = tid; s < 4096; s += 256) pacc[s] = 0.f;
  const int* mrow = mask + (b << 12);

  for (int h = 0; h < 16; ++h) {
    __syncthreads();
    if (tid < 64) qs[tid] = Qp[((size_t)(b * 512 + t)) * 1024 + h * 64 + tid];
    __syncthreads();
    for (int s = tid; s < 4096; s += 256) {
      const float* krow = Kp + ((size_t)((b << 12) + s)) * 1024 + h * 64;
      float d = 0.f;
#pragma unroll
      for (int kk = 0; kk < 64; kk += 4) {
        f32x4 kv = *(const f32x4*)(krow + kk);
#pragma unroll
        for (int j = 0; j < 4; ++j) d += qs[kk + j] * kv[j];
      }
      sc[s] = (mrow[s] != 0) ? d * 0.125f : -1.0e9f;
    }
    __syncthreads();
    float mx = -3.0e38f;
    for (int s = tid; s < 4096; s += 256) mx = fmaxf(mx, sc[s]);
    red[tid] = mx;
    __syncthreads();
    for (int off = 128; off; off >>= 1) {
      if (tid < off) red[tid] = fmaxf(red[tid], red[tid + off]);
      __syncthreads();
    }
    float m = red[0];
    __syncthreads();
    float sm = 0.f;
    for (int s = tid; s < 4096; s += 256) {
      float p = __expf(sc[s] - m);
      sc[s] = p;
      sm += p;
    }
    red[tid] = sm;
    __syncthreads();
    for (int off = 128; off; off >>= 1) {
      if (tid < off) red[tid] += red[tid + off];
      __syncthreads();
    }
    float il = 1.0f / red[0];
    for (int s = tid; s < 4096; s += 256) pacc[s] += sc[s] * il * 0.0625f;
    float o = 0.f;
    const bf16* vb = Vp + ((size_t)((b << 12) + wv * 1024)) * 1024 + h * 64 + lane;
    for (int s = 0; s < 1024; ++s) o += sc[wv * 1024 + s] * (float)vb[(size_t)s * 1024];
    po[wv][lane] = o;
    __syncthreads();
    if (tid < 64) {
      float oo = (po[0][tid] + po[1][tid] + po[2][tid] + po[3][tid]) * il;
      Oatt[((size_t)(b * 512 + t)) * 1024 + h * 64 + tid] = oo;
    }
  }
  __syncthreads();
  for (int s = tid; s < 4096; s += 256)
    prov[((size_t)(b * 512 + t)) * 4096 + s] = pacc[s];
}

// ---------------------------------------------------------------------------
extern "C" void kernel_launch(void* const* d_in, const int* in_sizes, int n_in,
                              void* d_out, int out_size, void* d_ws, size_t ws_size,
                              hipStream_t stream) {
  const float* query = (const float*)d_in[0];
  const float* key = (const float*)d_in[1];
  const float* value = (const float*)d_in[2];
  const int* amask = (const int*)d_in[3];
  const int* segid = (const int*)d_in[4];
  const float* Wq = (const float*)d_in[5];
  const float* bq = (const float*)d_in[6];
  const float* Wk = (const float*)d_in[7];
  const float* bk = (const float*)d_in[8];
  const float* Wv = (const float*)d_in[9];
  const float* bv = (const float*)d_in[10];
  const float* Wo = (const float*)d_in[11];
  const float* bo = (const float*)d_in[12];
  const float* semb = (const float*)d_in[13];

  char* ws = (char*)d_ws;
  float* outAtt = (float*)d_out;                  // [4,512,1024] f32
  float* outProv = outAtt + (size_t)2048 * 1024;  // [4,512,4096] f32

  if (ws_size >= (656ull << 20)) {
    // Fast path: materialized-scores attention.
    float* Qp = (float*)ws;                        //   8 MB  [2048,1024] f32
    float* Kp = (float*)(ws + (8ull << 20));       //  64 MB  [16384,1024] f32
    float* Vpf = (float*)(ws + (72ull << 20));     //  64 MB  [16384,1024] f32
    float* OatF = (float*)(ws + (136ull << 20));   //   8 MB  [2048,1024] f32
    float* Sc = (float*)(ws + (144ull << 20));     // 512 MB  [64*512,4096] f32

    gemm_f32<float><<<16 * 8, 256, 0, stream>>>(query, Wq, bq, Qp, 2048, 0, nullptr, nullptr);
    gemm_f32<float><<<128 * 8, 256, 0, stream>>>(key, Wk, bk, Kp, 16384, 1, segid, semb);
    gemm_f32<float><<<128 * 8, 256, 0, stream>>>(value, Wv, bv, Vpf, 16384, 0, nullptr, nullptr);
    qk_scores<<<8192, 256, 0, stream>>>(Qp, Kp, amask, Sc);
    softmax_prov<<<2048, 256, 0, stream>>>(Sc, outProv);
    pv_gemm<<<256, 256, 0, stream>>>(Sc, Vpf, OatF);
    gemm_f32<float><<<16 * 8, 256, 0, stream>>>(OatF, Wo, bo, outAtt, 2048, 0, nullptr, nullptr);
  } else {
    // Fallback: previous verified path.
    float* Qp = (float*)ws;                       // 8 MB
    float* Kp = (float*)(ws + (8ull << 20));      // 64 MB
    bf16* Vp = (bf16*)(ws + (72ull << 20));       // 32 MB
    float* OatF = (float*)(ws + (104ull << 20));  // 8 MB

    gemm_f32<float><<<16 * 8, 256, 0, stream>>>(query, Wq, bq, Qp, 2048, 0, nullptr, nullptr);
    gemm_f32<float><<<128 * 8, 256, 0, stream>>>(key, Wk, bk, Kp, 16384, 1, segid, semb);
    gemm_f32<bf16><<<128 * 8, 256, 0, stream>>>(value, Wv, bv, Vp, 16384, 0, nullptr, nullptr);
    attn_naive<<<2048, 256, 0, stream>>>(Qp, Kp, Vp, amask, OatF, outProv);
    gemm_f32<float><<<16 * 8, 256, 0, stream>>>(OatF, Wo, bo, outAtt, 2048, 0, nullptr, nullptr);
  }
}

// Round 2
// 2848.142 us; speedup vs baseline: 2.2476x; 2.2476x over previous
//
#include <hip/hip_runtime.h>

typedef __bf16 bf16;
typedef __attribute__((ext_vector_type(8))) __bf16 bf16x8;
typedef __attribute__((ext_vector_type(4))) float f32x4;

// XOR swizzle: spread rows-8-apart across banks (row stride ≡ 4 mod 32 banks
// otherwise). Flips col bits [2:4]; preserves 4-float (16B) alignment.
__device__ __forceinline__ int swz(int r, int c) {
  return c ^ (((r >> 3) & 7) << 2);
}

// ---------------------------------------------------------------------------
// GEMM: out[M][1024](OUT) = A[M][1024](f32) @ W[1024][1024](f32) + bias(f32)
// (+ seg_emb gather if mode==1). Pure f32 VALU core: 16x16 threads, each an
// 8x8 micro-tile of a 128x128 block tile. UNCHANGED from verified version.
// ---------------------------------------------------------------------------
template <typename OUT>
__global__ __launch_bounds__(256, 2) void gemm_f32(
    const float* __restrict__ A, const float* __restrict__ W,
    const float* __restrict__ bias, OUT* __restrict__ out, int M, int mode,
    const int* __restrict__ segids, const float* __restrict__ segemb) {
  __shared__ __align__(16) float As[128][36];
  __shared__ __align__(16) float Bs[32][132];

  int tid = threadIdx.x;
  int tx = tid & 15, ty = tid >> 4;
  int nTilesM = M >> 7;
  int bm = blockIdx.x % nTilesM, bn = blockIdx.x / nTilesM;
  int m0 = bm * 128, n0 = bn * 128;

  float acc[8][8];
#pragma unroll
  for (int i = 0; i < 8; i++)
#pragma unroll
    for (int j = 0; j < 8; j++) acc[i][j] = 0.f;

  for (int k0 = 0; k0 < 1024; k0 += 32) {
#pragma unroll
    for (int u = tid; u < 512; u += 256) {
      int r = u >> 2, c = (u & 3) * 8;
      const float* src = A + (size_t)(m0 + r) * 1024 + k0 + c;
      *(f32x4*)&As[r][c] = *(const f32x4*)src;
      *(f32x4*)&As[r][c + 4] = *(const f32x4*)(src + 4);
    }
#pragma unroll
    for (int u = tid; u < 512; u += 256) {
      int r = u >> 4, cc = (u & 15) * 8;
      const float* src = W + (size_t)(k0 + r) * 1024 + n0 + cc;
      *(f32x4*)&Bs[r][cc] = *(const f32x4*)src;
      *(f32x4*)&Bs[r][cc + 4] = *(const f32x4*)(src + 4);
    }
    __syncthreads();
#pragma unroll
    for (int kk = 0; kk < 32; kk++) {
      float av[8], bv[8];
#pragma unroll
      for (int i = 0; i < 8; i++) av[i] = As[ty * 8 + i][kk];
#pragma unroll
      for (int j = 0; j < 8; j++) bv[j] = Bs[kk][tx * 8 + j];
#pragma unroll
      for (int i = 0; i < 8; i++)
#pragma unroll
        for (int j = 0; j < 8; j++) acc[i][j] += av[i] * bv[j];
    }
    __syncthreads();
  }

#pragma unroll
  for (int i = 0; i < 8; i++) {
    int m = m0 + ty * 8 + i;
    int seg = (mode == 1) ? segids[m] : 0;
#pragma unroll
    for (int j = 0; j < 8; j++) {
      int n = n0 + tx * 8 + j;
      float v = acc[i][j] + bias[n];
      if (mode == 1) v += segemb[(size_t)seg * 1024 + n];
      out[(size_t)m * 1024 + n] = (OUT)v;
    }
  }
}

// ---------------------------------------------------------------------------
// Scores for a (head-group, t-range) chunk:
// Sc[bg*TC + (t-tBase)][4096] = mask ? (Q[b,t,h*64:].K[b,s,h*64:])*0.125 : -1e9
// where bg = b*G+g, h = h0+g. NT-GEMM K=64 single pass, tile 128t x 128s.
// LDS columns XOR-swizzled (else K-fragment read is a 16-way bank conflict:
// rows 8 apart, row stride 68 ≡ 4 mod 32).
// ---------------------------------------------------------------------------
__global__ __launch_bounds__(256, 2) void qk_scores(
    const float* __restrict__ Qp, const float* __restrict__ Kp,
    const int* __restrict__ mask, float* __restrict__ Sc,
    int G, int TC, int h0, int tBase) {
  __shared__ __align__(16) float Qs[128][68];
  __shared__ __align__(16) float Ks[128][68];

  int tid = threadIdx.x;
  int tx = tid & 15, ty = tid >> 4;
  int tiles_t = TC >> 7;  // 1, 2 or 4
  int bid = blockIdx.x;
  int rest = bid % (tiles_t * 32);
  int bg = bid / (tiles_t * 32);
  int tm = rest % tiles_t, sn = rest / tiles_t;
  int b = bg / G, g = bg % G, h = h0 + g;
  int t0 = tBase + (tm << 7), s0 = sn << 7;
  int tl0 = t0 - tBase + bg * TC;  // local Sc row base for r=0

  // stage Q[128][64] and K[128][64] (h-slice), swizzled
#pragma unroll
  for (int u = tid; u < 512; u += 256) {
    int r = u >> 2, c = (u & 3) << 4;
    const float* qsrc = Qp + (((size_t)((b << 9) + t0 + r)) << 10) + (h << 6) + c;
    const float* ksrc = Kp + (((size_t)((b << 12) + s0 + r)) << 10) + (h << 6) + c;
#pragma unroll
    for (int q4 = 0; q4 < 4; ++q4) {
      *(f32x4*)&Qs[r][swz(r, c + q4 * 4)] = *(const f32x4*)(qsrc + q4 * 4);
      *(f32x4*)&Ks[r][swz(r, c + q4 * 4)] = *(const f32x4*)(ksrc + q4 * 4);
    }
  }
  __syncthreads();

  float acc[8][8];
#pragma unroll
  for (int i = 0; i < 8; i++)
#pragma unroll
    for (int j = 0; j < 8; j++) acc[i][j] = 0.f;

  // r>>3 == ty (resp. tx) for all fragment rows, so one XOR per kk per operand
#pragma unroll 8
  for (int kk = 0; kk < 64; ++kk) {
    int kq = kk ^ ((ty & 7) << 2);
    int kx = kk ^ ((tx & 7) << 2);
    float av[8], bv[8];
#pragma unroll
    for (int i = 0; i < 8; i++) av[i] = Qs[ty * 8 + i][kq];
#pragma unroll
    for (int j = 0; j < 8; j++) bv[j] = Ks[tx * 8 + j][kx];
#pragma unroll
    for (int i = 0; i < 8; i++)
#pragma unroll
      for (int j = 0; j < 8; j++) acc[i][j] += av[i] * bv[j];
  }

  const int* mrow = mask + (b << 12) + s0 + tx * 8;
  bool mk[8];
#pragma unroll
  for (int j = 0; j < 8; j++) mk[j] = (mrow[j] != 0);

#pragma unroll
  for (int i = 0; i < 8; i++) {
    size_t row = (((size_t)(tl0 + ty * 8 + i)) << 12) + s0 + tx * 8;
    f32x4 v0, v1;
#pragma unroll
    for (int j = 0; j < 4; j++) {
      v0[j] = mk[j] ? acc[i][j] * 0.125f : -1.0e9f;
      v1[j] = mk[4 + j] ? acc[i][4 + j] * 0.125f : -1.0e9f;
    }
    *(f32x4*)&Sc[row] = v0;
    *(f32x4*)&Sc[row + 4] = v1;
  }
}

// ---------------------------------------------------------------------------
// Softmax (exact: max, __expf, sum — same arithmetic as the verified naive
// kernel) + provenance. Block per (b, t-in-chunk); loops the G heads of the
// chunk; normalizes Sc IN PLace; provenance accumulated in LDS across the
// chunk's heads, then init/accumulated into global prov (h0==0 → store).
// ---------------------------------------------------------------------------
__global__ __launch_bounds__(256) void softmax_prov(
    float* __restrict__ Sc, float* __restrict__ prov,
    int G, int TC, int h0, int tBase) {
  __shared__ __align__(16) float rowb[4096];
  __shared__ __align__(16) float pacc[4096];
  __shared__ float red[4];

  int tid = threadIdx.x, wv = tid >> 6;
  int bid = blockIdx.x;
  int b = bid / TC, tl = bid % TC;
  int t = tBase + tl;

#pragma unroll
  for (int it = 0; it < 4; ++it) {
    int s = (tid << 2) + (it << 10);
    pacc[s] = 0.f; pacc[s + 1] = 0.f; pacc[s + 2] = 0.f; pacc[s + 3] = 0.f;
  }

  for (int g = 0; g < G; ++g) {
    size_t base = ((size_t)((b * G + g) * TC + tl)) << 12;
    float mx = -3.0e38f;
#pragma unroll
    for (int it = 0; it < 4; ++it) {
      int s = (tid << 2) + (it << 10);
      f32x4 v = *(const f32x4*)&Sc[base + s];
      *(f32x4*)&rowb[s] = v;
      mx = fmaxf(fmaxf(fmaxf(mx, v[0]), v[1]), fmaxf(v[2], v[3]));
    }
#pragma unroll
    for (int o = 32; o; o >>= 1) mx = fmaxf(mx, __shfl_xor(mx, o));
    if ((tid & 63) == 0) red[wv] = mx;
    __syncthreads();
    float m = fmaxf(fmaxf(red[0], red[1]), fmaxf(red[2], red[3]));

    float sm = 0.f;
#pragma unroll
    for (int it = 0; it < 4; ++it) {
      int s = (tid << 2) + (it << 10);
      f32x4 v = *(const f32x4*)&rowb[s];
      f32x4 p;
      p[0] = __expf(v[0] - m);
      p[1] = __expf(v[1] - m);
      p[2] = __expf(v[2] - m);
      p[3] = __expf(v[3] - m);
      *(f32x4*)&rowb[s] = p;
      sm += (p[0] + p[1]) + (p[2] + p[3]);
    }
#pragma unroll
    for (int o = 32; o; o >>= 1) sm += __shfl_xor(sm, o);
    __syncthreads();  // all reads of red (for m) done before overwrite
    if ((tid & 63) == 0) red[wv] = sm;
    __syncthreads();
    float il = 1.0f / (((red[0] + red[1]) + (red[2] + red[3])));

#pragma unroll
    for (int it = 0; it < 4; ++it) {
      int s = (tid << 2) + (it << 10);
      f32x4 p = *(const f32x4*)&rowb[s];
      f32x4 pn;
      pn[0] = p[0] * il; pn[1] = p[1] * il;
      pn[2] = p[2] * il; pn[3] = p[3] * il;
      *(f32x4*)&Sc[base + s] = pn;
      f32x4 pa = *(const f32x4*)&pacc[s];
      pa[0] += pn[0] * 0.0625f; pa[1] += pn[1] * 0.0625f;
      pa[2] += pn[2] * 0.0625f; pa[3] += pn[3] * 0.0625f;
      *(f32x4*)&pacc[s] = pa;
    }
    __syncthreads();  // il reads done before next g overwrites red
  }

  size_t pbase = (((size_t)((b << 9) + t)) << 12);
#pragma unroll
  for (int it = 0; it < 4; ++it) {
    int s = (tid << 2) + (it << 10);
    f32x4 pa = *(const f32x4*)&pacc[s];
    if (h0 != 0) {
      f32x4 old = *(const f32x4*)&prov[pbase + s];
      pa[0] += old[0]; pa[1] += old[1]; pa[2] += old[2]; pa[3] += old[3];
    }
    *(f32x4*)&prov[pbase + s] = pa;
  }
}

// ---------------------------------------------------------------------------
// PV: Oat[b,t,h*64+d] = sum_s P[bg*TC + t-tBase][s] * V[b,s,h*64+d].
// Tile 64t x 64d, thread = 4x4 micro-tile (16x16 threads). LDS reads are
// broadcast across tx (P) / contiguous (V) — no swizzle needed.
// ---------------------------------------------------------------------------
template <typename VT>
__global__ __launch_bounds__(256, 4) void pv_gemm(
    const float* __restrict__ P, const VT* __restrict__ Vp,
    float* __restrict__ Oat, int G, int TC, int h0, int tBase) {
  __shared__ __align__(16) float Ps[64][36];
  __shared__ __align__(16) float Vs[32][68];

  int tid = threadIdx.x, tx = tid & 15, ty = tid >> 4;
  int ntt = TC >> 6;
  int bid = blockIdx.x;
  int tt = bid % ntt, bg = bid / ntt;
  int b = bg / G, g = bg % G, h = h0 + g;
  int tl0 = tt << 6;

  float acc[4][4];
#pragma unroll
  for (int i = 0; i < 4; i++)
#pragma unroll
    for (int j = 0; j < 4; j++) acc[i][j] = 0.f;

  for (int k0 = 0; k0 < 4096; k0 += 32) {
    {
      int r = tid >> 2, c = (tid & 3) << 3;
      const float* src = P + (((size_t)(bg * TC + tl0 + r)) << 12) + k0 + c;
      *(f32x4*)&Ps[r][c] = *(const f32x4*)src;
      *(f32x4*)&Ps[r][c + 4] = *(const f32x4*)(src + 4);
    }
    {
      int r = tid >> 3, c = (tid & 7) << 3;
      const VT* src = Vp + (((size_t)((b << 12) + k0 + r)) << 10) + (h << 6) + c;
      if constexpr (sizeof(VT) == 4) {
        *(f32x4*)&Vs[r][c] = *(const f32x4*)src;
        *(f32x4*)&Vs[r][c + 4] = *(const f32x4*)(src + 4);
      } else {
        bf16x8 v = *(const bf16x8*)src;
#pragma unroll
        for (int j = 0; j < 8; j++) Vs[r][c + j] = (float)v[j];
      }
    }
    __syncthreads();
#pragma unroll
    for (int kk = 0; kk < 32; ++kk) {
      float av[4], bv[4];
#pragma unroll
      for (int i = 0; i < 4; i++) av[i] = Ps[ty * 4 + i][kk];
#pragma unroll
      for (int j = 0; j < 4; j++) bv[j] = Vs[kk][tx * 4 + j];
#pragma unroll
      for (int i = 0; i < 4; i++)
#pragma unroll
        for (int j = 0; j < 4; j++) acc[i][j] += av[i] * bv[j];
    }
    __syncthreads();
  }

#pragma unroll
  for (int i = 0; i < 4; i++) {
    int t = tBase + tl0 + ty * 4 + i;
    f32x4 v;
#pragma unroll
    for (int j = 0; j < 4; j++) v[j] = acc[i][j];
    *(f32x4*)&Oat[(((size_t)((b << 9) + t)) << 10) + (h << 6) + (tx << 2)] = v;
  }
}

// ---------------------------------------------------------------------------
// Fallback: previous verified naive attention (used only if ws too small).
// ---------------------------------------------------------------------------
__global__ __launch_bounds__(256) void attn_naive(
    const float* __restrict__ Qp, const float* __restrict__ Kp,
    const bf16* __restrict__ Vp, const int* __restrict__ mask,
    float* __restrict__ Oatt, float* __restrict__ prov) {
  int bt = blockIdx.x;
  int b = bt >> 9, t = bt & 511;
  __shared__ float qs[64];
  __shared__ float sc[4096];
  __shared__ float pacc[4096];
  __shared__ float red[256];
  __shared__ float po[4][64];
  int tid = threadIdx.x, wv = tid >> 6, lane = tid & 63;

  for (int s = tid; s < 4096; s += 256) pacc[s] = 0.f;
  const int* mrow = mask + (b << 12);

  for (int h = 0; h < 16; ++h) {
    __syncthreads();
    if (tid < 64) qs[tid] = Qp[((size_t)(b * 512 + t)) * 1024 + h * 64 + tid];
    __syncthreads();
    for (int s = tid; s < 4096; s += 256) {
      const float* krow = Kp + ((size_t)((b << 12) + s)) * 1024 + h * 64;
      float d = 0.f;
#pragma unroll
      for (int kk = 0; kk < 64; kk += 4) {
        f32x4 kv = *(const f32x4*)(krow + kk);
#pragma unroll
        for (int j = 0; j < 4; ++j) d += qs[kk + j] * kv[j];
      }
      sc[s] = (mrow[s] != 0) ? d * 0.125f : -1.0e9f;
    }
    __syncthreads();
    float mx = -3.0e38f;
    for (int s = tid; s < 4096; s += 256) mx = fmaxf(mx, sc[s]);
    red[tid] = mx;
    __syncthreads();
    for (int off = 128; off; off >>= 1) {
      if (tid < off) red[tid] = fmaxf(red[tid], red[tid + off]);
      __syncthreads();
    }
    float m = red[0];
    __syncthreads();
    float sm = 0.f;
    for (int s = tid; s < 4096; s += 256) {
      float p = __expf(sc[s] - m);
      sc[s] = p;
      sm += p;
    }
    red[tid] = sm;
    __syncthreads();
    for (int off = 128; off; off >>= 1) {
      if (tid < off) red[tid] += red[tid + off];
      __syncthreads();
    }
    float il = 1.0f / red[0];
    for (int s = tid; s < 4096; s += 256) pacc[s] += sc[s] * il * 0.0625f;
    float o = 0.f;
    const bf16* vb = Vp + ((size_t)((b << 12) + wv * 1024)) * 1024 + h * 64 + lane;
    for (int s = 0; s < 1024; ++s) o += sc[wv * 1024 + s] * (float)vb[(size_t)s * 1024];
    po[wv][lane] = o;
    __syncthreads();
    if (tid < 64) {
      float oo = (po[0][tid] + po[1][tid] + po[2][tid] + po[3][tid]) * il;
      Oatt[((size_t)(b * 512 + t)) * 1024 + h * 64 + tid] = oo;
    }
  }
  __syncthreads();
  for (int s = tid; s < 4096; s += 256)
    prov[((size_t)(b * 512 + t)) * 4096 + s] = pacc[s];
}

// ---------------------------------------------------------------------------
extern "C" void kernel_launch(void* const* d_in, const int* in_sizes, int n_in,
                              void* d_out, int out_size, void* d_ws, size_t ws_size,
                              hipStream_t stream) {
  const float* query = (const float*)d_in[0];
  const float* key = (const float*)d_in[1];
  const float* value = (const float*)d_in[2];
  const int* amask = (const int*)d_in[3];
  const int* segid = (const int*)d_in[4];
  const float* Wq = (const float*)d_in[5];
  const float* bq = (const float*)d_in[6];
  const float* Wk = (const float*)d_in[7];
  const float* bk = (const float*)d_in[8];
  const float* Wv = (const float*)d_in[9];
  const float* bv = (const float*)d_in[10];
  const float* Wo = (const float*)d_in[11];
  const float* bo = (const float*)d_in[12];
  const float* semb = (const float*)d_in[13];

  char* ws = (char*)d_ws;
  float* outAtt = (float*)d_out;                  // [4,512,1024] f32
  float* outProv = outAtt + (size_t)2048 * 1024;  // [4,512,4096] f32

  const size_t MB = 1ull << 20;
  // Choose the largest score-chunk that fits: Sc bytes = 4*G*TC*4096*4.
  // Base ws: Qp 8 + Kp 64 + V 32(bf16)/64(f32) + OatF 8.
  static const int cand[7][2] = {{16, 512}, {8, 512}, {4, 512}, {2, 512},
                                 {1, 512},  {1, 256}, {1, 128}};
  int G = 0, TC = 0;
  size_t scBytes = 0;
  for (int ci = 0; ci < 7; ++ci) {
    size_t sb = (size_t)4 * cand[ci][0] * cand[ci][1] * 4096 * 4;
    if (112 * MB + sb <= ws_size) { G = cand[ci][0]; TC = cand[ci][1]; scBytes = sb; break; }
  }

  if (G > 0) {
    bool vf32 = (144 * MB + scBytes <= ws_size);
    float* Qp = (float*)ws;                    //  8 MB [2048,1024] f32
    float* Kp = (float*)(ws + 8 * MB);         // 64 MB [16384,1024] f32
    float* Vpf = (float*)(ws + 72 * MB);       // 64 MB f32 (or 32 MB bf16)
    bf16* Vpb = (bf16*)(ws + 72 * MB);
    float* OatF = (float*)(ws + (vf32 ? 136 : 104) * MB);  // 8 MB
    float* Sc = (float*)(ws + (vf32 ? 144 : 112) * MB);

    gemm_f32<float><<<16 * 8, 256, 0, stream>>>(query, Wq, bq, Qp, 2048, 0, nullptr, nullptr);
    gemm_f32<float><<<128 * 8, 256, 0, stream>>>(key, Wk, bk, Kp, 16384, 1, segid, semb);
    if (vf32)
      gemm_f32<float><<<128 * 8, 256, 0, stream>>>(value, Wv, bv, Vpf, 16384, 0, nullptr, nullptr);
    else
      gemm_f32<bf16><<<128 * 8, 256, 0, stream>>>(value, Wv, bv, Vpb, 16384, 0, nullptr, nullptr);

    int nHC = 16 / G, nTCk = 512 / TC;
    for (int hc = 0; hc < nHC; ++hc) {
      int h0 = hc * G;
      for (int tc = 0; tc < nTCk; ++tc) {
        int tBase = tc * TC;
        qk_scores<<<4 * G * (TC >> 7) * 32, 256, 0, stream>>>(
            Qp, Kp, amask, Sc, G, TC, h0, tBase);
        softmax_prov<<<4 * TC, 256, 0, stream>>>(Sc, outProv, G, TC, h0, tBase);
        if (vf32)
          pv_gemm<float><<<4 * G * (TC >> 6), 256, 0, stream>>>(
              Sc, Vpf, OatF, G, TC, h0, tBase);
        else
          pv_gemm<bf16><<<4 * G * (TC >> 6), 256, 0, stream>>>(
              Sc, Vpb, OatF, G, TC, h0, tBase);
      }
    }
    gemm_f32<float><<<16 * 8, 256, 0, stream>>>(OatF, Wo, bo, outAtt, 2048, 0, nullptr, nullptr);
  } else {
    // Fallback: previous verified path (needs 112 MB).
    float* Qp = (float*)ws;                   // 8 MB
    float* Kp = (float*)(ws + 8 * MB);        // 64 MB
    bf16* Vp = (bf16*)(ws + 72 * MB);         // 32 MB
    float* OatF = (float*)(ws + 104 * MB);    // 8 MB

    gemm_f32<float><<<16 * 8, 256, 0, stream>>>(query, Wq, bq, Qp, 2048, 0, nullptr, nullptr);
    gemm_f32<float><<<128 * 8, 256, 0, stream>>>(key, Wk, bk, Kp, 16384, 1, segid, semb);
    gemm_f32<bf16><<<128 * 8, 256, 0, stream>>>(value, Wv, bv, Vp, 16384, 0, nullptr, nullptr);
    attn_naive<<<2048, 256, 0, stream>>>(Qp, Kp, Vp, amask, OatF, outProv);
    gemm_f32<float><<<16 * 8, 256, 0, stream>>>(OatF, Wo, bo, outAtt, 2048, 0, nullptr, nullptr);
  }
}

// Round 3
// 2711.132 us; speedup vs baseline: 2.3612x; 1.0505x over previous
//
#include <hip/hip_runtime.h>

typedef __bf16 bf16;
typedef __attribute__((ext_vector_type(8))) __bf16 bf16x8;
typedef __attribute__((ext_vector_type(4))) __bf16 bf16x4;
typedef __attribute__((ext_vector_type(4))) float f32x4;

// ---------------------------------------------------------------------------
// GEMM: out[M][1024](OUT) = A[M][1024](f32) @ W[1024][1024](f32) + bias(f32)
// (+ seg_emb gather if mode==1). f32 VALU core, 16x16 threads, 8x8 micro-tile
// of a 128x128 block tile. A staged TRANSPOSED so both fragments are b128:
//   av: AsT[kk][ty*8]   -> 4 per-wave addrs, distinct banks (broadcast, free)
//   bv: Bs[kk][tx*4], Bs[kk][64+tx*4] -> 16B stride = 2-way (free)
// Accumulation order per output element identical to verified version.
// ---------------------------------------------------------------------------
template <typename OUT>
__global__ __launch_bounds__(256, 2) void gemm_f32(
    const float* __restrict__ A, const float* __restrict__ W,
    const float* __restrict__ bias, OUT* __restrict__ out, int M, int mode,
    const int* __restrict__ segids, const float* __restrict__ segemb) {
  __shared__ __align__(16) float AsT[32][132];  // [k][m]
  __shared__ __align__(16) float Bs[32][132];   // [k][n]

  int tid = threadIdx.x;
  int tx = tid & 15, ty = tid >> 4;
  int nTilesM = M >> 7;
  int bm = blockIdx.x % nTilesM, bn = blockIdx.x / nTilesM;
  int m0 = bm * 128, n0 = bn * 128;

  int sm = tid & 127;         // staging: m row
  int skb = (tid >> 7) * 16;  // staging: k base (0 or 16)

  float acc[8][8];
#pragma unroll
  for (int i = 0; i < 8; i++)
#pragma unroll
    for (int j = 0; j < 8; j++) acc[i][j] = 0.f;

  for (int k0 = 0; k0 < 1024; k0 += 32) {
    {  // A tile -> AsT (transposed). 16 f32/thread.
      const float* src = A + (size_t)(m0 + sm) * 1024 + k0 + skb;
      f32x4 a0 = *(const f32x4*)src;
      f32x4 a1 = *(const f32x4*)(src + 4);
      f32x4 a2 = *(const f32x4*)(src + 8);
      f32x4 a3 = *(const f32x4*)(src + 12);
#pragma unroll
      for (int j = 0; j < 4; j++) {
        AsT[skb + j][sm] = a0[j];
        AsT[skb + 4 + j][sm] = a1[j];
        AsT[skb + 8 + j][sm] = a2[j];
        AsT[skb + 12 + j][sm] = a3[j];
      }
    }
#pragma unroll
    for (int u = tid; u < 512; u += 256) {  // B tile row-major
      int r = u >> 4, cc = (u & 15) * 8;
      const float* src = W + (size_t)(k0 + r) * 1024 + n0 + cc;
      *(f32x4*)&Bs[r][cc] = *(const f32x4*)src;
      *(f32x4*)&Bs[r][cc + 4] = *(const f32x4*)(src + 4);
    }
    __syncthreads();
#pragma unroll
    for (int kk = 0; kk < 32; kk++) {
      f32x4 av0 = *(const f32x4*)&AsT[kk][ty * 8];
      f32x4 av1 = *(const f32x4*)&AsT[kk][ty * 8 + 4];
      f32x4 bv0 = *(const f32x4*)&Bs[kk][tx * 4];
      f32x4 bv1 = *(const f32x4*)&Bs[kk][64 + tx * 4];
      float av[8] = {av0[0], av0[1], av0[2], av0[3],
                     av1[0], av1[1], av1[2], av1[3]};
#pragma unroll
      for (int i = 0; i < 8; i++) {
#pragma unroll
        for (int j = 0; j < 4; j++) {
          acc[i][j] += av[i] * bv0[j];
          acc[i][4 + j] += av[i] * bv1[j];
        }
      }
    }
    __syncthreads();
  }

#pragma unroll
  for (int i = 0; i < 8; i++) {
    int m = m0 + ty * 8 + i;
    int seg = (mode == 1) ? segids[m] : 0;
#pragma unroll
    for (int jh = 0; jh < 2; jh++) {
#pragma unroll
      for (int j = 0; j < 4; j++) {
        int n = n0 + jh * 64 + tx * 4 + j;
        float v = acc[i][jh * 4 + j] + bias[n];
        if (mode == 1) v += segemb[(size_t)seg * 1024 + n];
        out[(size_t)m * 1024 + n] = (OUT)v;
      }
    }
  }
}

// ---------------------------------------------------------------------------
// Scores chunk: Sc[bg*TC + (t-tBase)][4096] =
//   mask ? (Q[b,t,h*64:].K[b,s,h*64:])*0.125 : -1e9 ; bg=b*G+g, h=h0+g.
// NT-GEMM K=64 single pass, tile 128t x 128s, Q/K staged TRANSPOSED.
// Fragments: av 2xb128 broadcast; bv 2xb128 split cols (tx*4, 64+tx*4).
// ---------------------------------------------------------------------------
__global__ __launch_bounds__(256, 2) void qk_scores(
    const float* __restrict__ Qp, const float* __restrict__ Kp,
    const int* __restrict__ mask, float* __restrict__ Sc,
    int G, int TC, int h0, int tBase) {
  __shared__ __align__(16) float QsT[64][132];  // [k][t]
  __shared__ __align__(16) float KsT[64][132];  // [k][s]

  int tid = threadIdx.x;
  int tx = tid & 15, ty = tid >> 4;
  int tiles_t = TC >> 7;
  int bid = blockIdx.x;
  int rest = bid % (tiles_t * 32);
  int bg = bid / (tiles_t * 32);
  int tm = rest % tiles_t, sn = rest / tiles_t;
  int b = bg / G, g = bg % G, h = h0 + g;
  int t0 = tBase + (tm << 7), s0 = sn << 7;
  int tl0 = t0 - tBase + bg * TC;

  int srow = tid & 127, skb = (tid >> 7) * 32;
  {
    const float* qsrc = Qp + (((size_t)((b << 9) + t0 + srow)) << 10) + (h << 6) + skb;
    const float* ksrc = Kp + (((size_t)((b << 12) + s0 + srow)) << 10) + (h << 6) + skb;
#pragma unroll
    for (int q4 = 0; q4 < 8; ++q4) {
      f32x4 qv = *(const f32x4*)(qsrc + q4 * 4);
      f32x4 kv = *(const f32x4*)(ksrc + q4 * 4);
#pragma unroll
      for (int j = 0; j < 4; ++j) {
        QsT[skb + q4 * 4 + j][srow] = qv[j];
        KsT[skb + q4 * 4 + j][srow] = kv[j];
      }
    }
  }
  __syncthreads();

  float acc[8][8];
#pragma unroll
  for (int i = 0; i < 8; i++)
#pragma unroll
    for (int j = 0; j < 8; j++) acc[i][j] = 0.f;

#pragma unroll 4
  for (int kk = 0; kk < 64; ++kk) {
    f32x4 av0 = *(const f32x4*)&QsT[kk][ty * 8];
    f32x4 av1 = *(const f32x4*)&QsT[kk][ty * 8 + 4];
    f32x4 bv0 = *(const f32x4*)&KsT[kk][tx * 4];
    f32x4 bv1 = *(const f32x4*)&KsT[kk][64 + tx * 4];
    float av[8] = {av0[0], av0[1], av0[2], av0[3],
                   av1[0], av1[1], av1[2], av1[3]};
#pragma unroll
    for (int i = 0; i < 8; i++) {
#pragma unroll
      for (int j = 0; j < 4; j++) {
        acc[i][j] += av[i] * bv0[j];
        acc[i][4 + j] += av[i] * bv1[j];
      }
    }
  }

  const int* mrow = mask + (b << 12) + s0;
  bool mk[8];
#pragma unroll
  for (int j = 0; j < 4; j++) {
    mk[j] = (mrow[tx * 4 + j] != 0);
    mk[4 + j] = (mrow[64 + tx * 4 + j] != 0);
  }

#pragma unroll
  for (int i = 0; i < 8; i++) {
    size_t row = (((size_t)(tl0 + ty * 8 + i)) << 12) + s0;
    f32x4 v0, v1;
#pragma unroll
    for (int j = 0; j < 4; j++) {
      v0[j] = mk[j] ? acc[i][j] * 0.125f : -1.0e9f;
      v1[j] = mk[4 + j] ? acc[i][4 + j] * 0.125f : -1.0e9f;
    }
    *(f32x4*)&Sc[row + tx * 4] = v0;
    *(f32x4*)&Sc[row + 64 + tx * 4] = v1;
  }
}

// ---------------------------------------------------------------------------
// Softmax (exact: max, __expf, sum — same arithmetic as verified) + prov.
// All-register row (16 f32/thread) — no LDS row buffer. PMODE 0: normalized
// P written f32 in place to Sc. PMODE 1: written bf16 to Pb (P in [0,1];
// bf16 rel err ~0.4% -> output err ~6e-5, well under tolerance).
// ---------------------------------------------------------------------------
template <int PMODE>
__global__ __launch_bounds__(256, 2) void softmax_prov(
    float* __restrict__ Sc, bf16* __restrict__ Pb, float* __restrict__ prov,
    int G, int TC, int h0, int tBase) {
  __shared__ float red[4];

  int tid = threadIdx.x, wv = tid >> 6;
  int bid = blockIdx.x;
  int b = bid / TC, tl = bid % TC;
  int t = tBase + tl;

  float pacc[16];
#pragma unroll
  for (int i = 0; i < 16; i++) pacc[i] = 0.f;

  for (int g = 0; g < G; ++g) {
    size_t base = ((size_t)((b * G + g) * TC + tl)) << 12;
    f32x4 v[4];
    float mx = -3.0e38f;
#pragma unroll
    for (int it = 0; it < 4; ++it) {
      int s = (tid << 2) + (it << 10);
      v[it] = *(const f32x4*)&Sc[base + s];
      mx = fmaxf(fmaxf(fmaxf(mx, v[it][0]), v[it][1]), fmaxf(v[it][2], v[it][3]));
    }
#pragma unroll
    for (int o = 32; o; o >>= 1) mx = fmaxf(mx, __shfl_xor(mx, o));
    if ((tid & 63) == 0) red[wv] = mx;
    __syncthreads();
    float m = fmaxf(fmaxf(red[0], red[1]), fmaxf(red[2], red[3]));
    __syncthreads();  // all m-reads done before red is reused for sums

    float sm = 0.f;
#pragma unroll
    for (int it = 0; it < 4; ++it) {
      f32x4 p;
      p[0] = __expf(v[it][0] - m);
      p[1] = __expf(v[it][1] - m);
      p[2] = __expf(v[it][2] - m);
      p[3] = __expf(v[it][3] - m);
      v[it] = p;
      sm += (p[0] + p[1]) + (p[2] + p[3]);
    }
#pragma unroll
    for (int o = 32; o; o >>= 1) sm += __shfl_xor(sm, o);
    if ((tid & 63) == 0) red[wv] = sm;
    __syncthreads();
    float il = 1.0f / (((red[0] + red[1]) + (red[2] + red[3])));
    __syncthreads();  // il reads done before next g overwrites red

#pragma unroll
    for (int it = 0; it < 4; ++it) {
      int s = (tid << 2) + (it << 10);
      f32x4 pn;
      pn[0] = v[it][0] * il;
      pn[1] = v[it][1] * il;
      pn[2] = v[it][2] * il;
      pn[3] = v[it][3] * il;
      if constexpr (PMODE == 1) {
        bf16x4 pb;
        pb[0] = (bf16)pn[0]; pb[1] = (bf16)pn[1];
        pb[2] = (bf16)pn[2]; pb[3] = (bf16)pn[3];
        *(bf16x4*)&Pb[base + s] = pb;
      } else {
        *(f32x4*)&Sc[base + s] = pn;
      }
      pacc[it * 4 + 0] += pn[0] * 0.0625f;
      pacc[it * 4 + 1] += pn[1] * 0.0625f;
      pacc[it * 4 + 2] += pn[2] * 0.0625f;
      pacc[it * 4 + 3] += pn[3] * 0.0625f;
    }
  }

  size_t pbase = (((size_t)((b << 9) + t)) << 12);
#pragma unroll
  for (int it = 0; it < 4; ++it) {
    int s = (tid << 2) + (it << 10);
    f32x4 pa;
    pa[0] = pacc[it * 4 + 0]; pa[1] = pacc[it * 4 + 1];
    pa[2] = pacc[it * 4 + 2]; pa[3] = pacc[it * 4 + 3];
    if (h0 != 0) {
      f32x4 old = *(const f32x4*)&prov[pbase + s];
      pa[0] += old[0]; pa[1] += old[1]; pa[2] += old[2]; pa[3] += old[3];
    }
    *(f32x4*)&prov[pbase + s] = pa;
  }
}

// ---------------------------------------------------------------------------
// PV: Oat[b,t,h*64+d] = sum_s P[...][s] * V[b,s,h*64+d]. Tile 64t x 64d,
// 4x4 micro-tile. P staged TRANSPOSED (PsT[k][t]) so av is b128 broadcast;
// bv is b128 2-way. K-accumulation order matches verified version.
// ---------------------------------------------------------------------------
template <typename PT, typename VT>
__global__ __launch_bounds__(256, 2) void pv_gemm(
    const PT* __restrict__ P, const VT* __restrict__ Vp,
    float* __restrict__ Oat, int G, int TC, int h0, int tBase) {
  __shared__ __align__(16) float PsT[32][68];  // [k][t]
  __shared__ __align__(16) float Vs[32][68];   // [k][d]

  int tid = threadIdx.x, tx = tid & 15, ty = tid >> 4;
  int ntt = TC >> 6;
  int bid = blockIdx.x;
  int tt = bid % ntt, bg = bid / ntt;
  int b = bg / G, g = bg % G, h = h0 + g;
  int tl0 = tt << 6;

  int st = tid & 63, sc = (tid >> 6) * 8;  // P staging: 8 elems/thread
  int vr = tid >> 3, vc = (tid & 7) * 8;   // V staging

  float acc[4][4];
#pragma unroll
  for (int i = 0; i < 4; i++)
#pragma unroll
    for (int j = 0; j < 4; j++) acc[i][j] = 0.f;

  for (int k0 = 0; k0 < 4096; k0 += 32) {
    {
      const PT* src = P + (((size_t)(bg * TC + tl0 + st)) << 12) + k0 + sc;
      if constexpr (sizeof(PT) == 2) {
        bf16x8 p8 = *(const bf16x8*)src;
#pragma unroll
        for (int j = 0; j < 8; j++) PsT[sc + j][st] = (float)p8[j];
      } else {
        f32x4 p0 = *(const f32x4*)src;
        f32x4 p1 = *(const f32x4*)(src + 4);
#pragma unroll
        for (int j = 0; j < 4; j++) {
          PsT[sc + j][st] = p0[j];
          PsT[sc + 4 + j][st] = p1[j];
        }
      }
    }
    {
      const VT* src = Vp + (((size_t)((b << 12) + k0 + vr)) << 10) + (h << 6) + vc;
      if constexpr (sizeof(VT) == 4) {
        *(f32x4*)&Vs[vr][vc] = *(const f32x4*)src;
        *(f32x4*)&Vs[vr][vc + 4] = *(const f32x4*)(src + 4);
      } else {
        bf16x8 v8 = *(const bf16x8*)src;
#pragma unroll
        for (int j = 0; j < 8; j++) Vs[vr][vc + j] = (float)v8[j];
      }
    }
    __syncthreads();
#pragma unroll
    for (int kk = 0; kk < 32; ++kk) {
      f32x4 av = *(const f32x4*)&PsT[kk][ty * 4];
      f32x4 bv = *(const f32x4*)&Vs[kk][tx * 4];
#pragma unroll
      for (int i = 0; i < 4; i++)
#pragma unroll
        for (int j = 0; j < 4; j++) acc[i][j] += av[i] * bv[j];
    }
    __syncthreads();
  }

#pragma unroll
  for (int i = 0; i < 4; i++) {
    int t = tBase + tl0 + ty * 4 + i;
    f32x4 v;
#pragma unroll
    for (int j = 0; j < 4; j++) v[j] = acc[i][j];
    *(f32x4*)&Oat[(((size_t)((b << 9) + t)) << 10) + (h << 6) + (tx << 2)] = v;
  }
}

// ---------------------------------------------------------------------------
// Fallback: original verified naive attention (only if ws < 120 MB).
// ---------------------------------------------------------------------------
__global__ __launch_bounds__(256) void attn_naive(
    const float* __restrict__ Qp, const float* __restrict__ Kp,
    const bf16* __restrict__ Vp, const int* __restrict__ mask,
    float* __restrict__ Oatt, float* __restrict__ prov) {
  int bt = blockIdx.x;
  int b = bt >> 9, t = bt & 511;
  __shared__ float qs[64];
  __shared__ float sc[4096];
  __shared__ float pacc[4096];
  __shared__ float red[256];
  __shared__ float po[4][64];
  int tid = threadIdx.x, wv = tid >> 6, lane = tid & 63;

  for (int s = tid; s < 4096; s += 256) pacc[s] = 0.f;
  const int* mrow = mask + (b << 12);

  for (int h = 0; h < 16; ++h) {
    __syncthreads();
    if (tid < 64) qs[tid] = Qp[((size_t)(b * 512 + t)) * 1024 + h * 64 + tid];
    __syncthreads();
    for (int s = tid; s < 4096; s += 256) {
      const float* krow = Kp + ((size_t)((b << 12) + s)) * 1024 + h * 64;
      float d = 0.f;
#pragma unroll
      for (int kk = 0; kk < 64; kk += 4) {
        f32x4 kv = *(const f32x4*)(krow + kk);
#pragma unroll
        for (int j = 0; j < 4; ++j) d += qs[kk + j] * kv[j];
      }
      sc[s] = (mrow[s] != 0) ? d * 0.125f : -1.0e9f;
    }
    __syncthreads();
    float mx = -3.0e38f;
    for (int s = tid; s < 4096; s += 256) mx = fmaxf(mx, sc[s]);
    red[tid] = mx;
    __syncthreads();
    for (int off = 128; off; off >>= 1) {
      if (tid < off) red[tid] = fmaxf(red[tid], red[tid + off]);
      __syncthreads();
    }
    float m = red[0];
    __syncthreads();
    float sm = 0.f;
    for (int s = tid; s < 4096; s += 256) {
      float p = __expf(sc[s] - m);
      sc[s] = p;
      sm += p;
    }
    red[tid] = sm;
    __syncthreads();
    for (int off = 128; off; off >>= 1) {
      if (tid < off) red[tid] += red[tid + off];
      __syncthreads();
    }
    float il = 1.0f / red[0];
    for (int s = tid; s < 4096; s += 256) pacc[s] += sc[s] * il * 0.0625f;
    float o = 0.f;
    const bf16* vb = Vp + ((size_t)((b << 12) + wv * 1024)) * 1024 + h * 64 + lane;
    for (int s = 0; s < 1024; ++s) o += sc[wv * 1024 + s] * (float)vb[(size_t)s * 1024];
    po[wv][lane] = o;
    __syncthreads();
    if (tid < 64) {
      float oo = (po[0][tid] + po[1][tid] + po[2][tid] + po[3][tid]) * il;
      Oatt[((size_t)(b * 512 + t)) * 1024 + h * 64 + tid] = oo;
    }
  }
  __syncthreads();
  for (int s = tid; s < 4096; s += 256)
    prov[((size_t)(b * 512 + t)) * 4096 + s] = pacc[s];
}

// ---------------------------------------------------------------------------
extern "C" void kernel_launch(void* const* d_in, const int* in_sizes, int n_in,
                              void* d_out, int out_size, void* d_ws, size_t ws_size,
                              hipStream_t stream) {
  const float* query = (const float*)d_in[0];
  const float* key = (const float*)d_in[1];
  const float* value = (const float*)d_in[2];
  const int* amask = (const int*)d_in[3];
  const int* segid = (const int*)d_in[4];
  const float* Wq = (const float*)d_in[5];
  const float* bq = (const float*)d_in[6];
  const float* Wk = (const float*)d_in[7];
  const float* bk = (const float*)d_in[8];
  const float* Wv = (const float*)d_in[9];
  const float* bv = (const float*)d_in[10];
  const float* Wo = (const float*)d_in[11];
  const float* bo = (const float*)d_in[12];
  const float* semb = (const float*)d_in[13];

  char* ws = (char*)d_ws;
  float* outAtt = (float*)d_out;                  // [4,512,1024] f32
  float* outProv = outAtt + (size_t)2048 * 1024;  // [4,512,4096] f32

  const size_t MB = 1ull << 20;
  static const int cand[7][2] = {{16, 512}, {8, 512}, {4, 512}, {2, 512},
                                 {1, 512},  {1, 256}, {1, 128}};
  int G = 0, TC = 0;
  size_t scBytes = 0;
  for (int ci = 0; ci < 7; ++ci) {
    size_t sb = (size_t)4 * cand[ci][0] * cand[ci][1] * 4096 * 4;
    if (112 * MB + sb <= ws_size) { G = cand[ci][0]; TC = cand[ci][1]; scBytes = sb; break; }
  }

  if (G > 0) {
    bool vf32 = (144 * MB + scBytes <= ws_size);
    size_t scOff = (vf32 ? 144 : 112) * MB;
    bool usePb = (scOff + scBytes + scBytes / 2 <= ws_size);

    float* Qp = (float*)ws;                    //  8 MB [2048,1024] f32
    float* Kp = (float*)(ws + 8 * MB);         // 64 MB [16384,1024] f32
    float* Vpf = (float*)(ws + 72 * MB);       // 64 MB f32 (or 32 MB bf16)
    bf16* Vpb = (bf16*)(ws + 72 * MB);
    float* OatF = (float*)(ws + (vf32 ? 136 : 104) * MB);  // 8 MB
    float* Sc = (float*)(ws + scOff);
    bf16* Pb = (bf16*)(ws + scOff + scBytes);

    gemm_f32<float><<<16 * 8, 256, 0, stream>>>(query, Wq, bq, Qp, 2048, 0, nullptr, nullptr);
    gemm_f32<float><<<128 * 8, 256, 0, stream>>>(key, Wk, bk, Kp, 16384, 1, segid, semb);
    if (vf32)
      gemm_f32<float><<<128 * 8, 256, 0, stream>>>(value, Wv, bv, Vpf, 16384, 0, nullptr, nullptr);
    else
      gemm_f32<bf16><<<128 * 8, 256, 0, stream>>>(value, Wv, bv, Vpb, 16384, 0, nullptr, nullptr);

    int nHC = 16 / G, nTCk = 512 / TC;
    for (int hc = 0; hc < nHC; ++hc) {
      int h0 = hc * G;
      for (int tc = 0; tc < nTCk; ++tc) {
        int tBase = tc * TC;
        qk_scores<<<4 * G * (TC >> 7) * 32, 256, 0, stream>>>(
            Qp, Kp, amask, Sc, G, TC, h0, tBase);
        if (usePb)
          softmax_prov<1><<<4 * TC, 256, 0, stream>>>(Sc, Pb, outProv, G, TC, h0, tBase);
        else
          softmax_prov<0><<<4 * TC, 256, 0, stream>>>(Sc, Pb, outProv, G, TC, h0, tBase);
        int pvGrid = 4 * G * (TC >> 6);
        if (usePb) {
          if (vf32)
            pv_gemm<bf16, float><<<pvGrid, 256, 0, stream>>>(Pb, Vpf, OatF, G, TC, h0, tBase);
          else
            pv_gemm<bf16, bf16><<<pvGrid, 256, 0, stream>>>(Pb, Vpb, OatF, G, TC, h0, tBase);
        } else {
          if (vf32)
            pv_gemm<float, float><<<pvGrid, 256, 0, stream>>>(Sc, Vpf, OatF, G, TC, h0, tBase);
          else
            pv_gemm<float, bf16><<<pvGrid, 256, 0, stream>>>(Sc, Vpb, OatF, G, TC, h0, tBase);
        }
      }
    }
    gemm_f32<float><<<16 * 8, 256, 0, stream>>>(OatF, Wo, bo, outAtt, 2048, 0, nullptr, nullptr);
  } else {
    // Fallback: original verified path (needs 112 MB).
    float* Qp = (float*)ws;                   // 8 MB
    float* Kp = (float*)(ws + 8 * MB);        // 64 MB
    bf16* Vp = (bf16*)(ws + 72 * MB);         // 32 MB
    float* OatF = (float*)(ws + 104 * MB);    // 8 MB

    gemm_f32<float><<<16 * 8, 256, 0, stream>>>(query, Wq, bq, Qp, 2048, 0, nullptr, nullptr);
    gemm_f32<float><<<128 * 8, 256, 0, stream>>>(key, Wk, bk, Kp, 16384, 1, segid, semb);
    gemm_f32<bf16><<<128 * 8, 256, 0, stream>>>(value, Wv, bv, Vp, 16384, 0, nullptr, nullptr);
    attn_naive<<<2048, 256, 0, stream>>>(Qp, Kp, Vp, amask, OatF, outProv);
    gemm_f32<float><<<16 * 8, 256, 0, stream>>>(OatF, Wo, bo, outAtt, 2048, 0, nullptr, nullptr);
  }
}

// Round 4
// 2036.161 us; speedup vs baseline: 3.1439x; 1.3315x over previous
//
#include <hip/hip_runtime.h>

typedef __bf16 bf16;
typedef __attribute__((ext_vector_type(8))) __bf16 bf16x8;
typedef __attribute__((ext_vector_type(4))) __bf16 bf16x4;
typedef __attribute__((ext_vector_type(4))) float f32x4;
typedef __attribute__((ext_vector_type(8))) short s16x8;

// ---------------------------------------------------------------------------
// wtrans: W[1024][1024] f32 (row-major [k][n]) -> WT_hi/WT_lo bf16 [n][k].
// One-shot per weight matrix (4 MB). hi = bf16(w); lo = bf16(w - hi).
// ---------------------------------------------------------------------------
__global__ __launch_bounds__(256) void wtrans(const float* __restrict__ W,
                                              bf16* __restrict__ Th,
                                              bf16* __restrict__ Tl) {
  __shared__ float Ts[64][65];
  int tid = threadIdx.x;
  int k0 = (blockIdx.x & 15) << 6, n0 = (blockIdx.x >> 4) << 6;
  int r = tid >> 2, c0 = (tid & 3) << 4;
#pragma unroll
  for (int j = 0; j < 16; j += 4) {
    f32x4 v = *(const f32x4*)&W[(size_t)(k0 + r) * 1024 + n0 + c0 + j];
#pragma unroll
    for (int q = 0; q < 4; ++q) Ts[r][c0 + j + q] = v[q];
  }
  __syncthreads();
  int nl = tid & 63, kq = (tid >> 6) << 4;
#pragma unroll
  for (int j = 0; j < 16; ++j) {
    float v = Ts[kq + j][nl];
    bf16 hi = (bf16)v;
    bf16 lo = (bf16)(v - (float)hi);
    Th[(size_t)(n0 + nl) * 1024 + k0 + kq + j] = hi;
    Tl[(size_t)(n0 + nl) * 1024 + k0 + kq + j] = lo;
  }
}

// ---------------------------------------------------------------------------
// MFMA GEMM via bf16 hi/lo split (bf16x3): out = A[M][1024] @ W[1024][1024]
// + bias (+seg_emb if mode==1). A·W ≈ Ah·Wh + Ah·Wl + Al·Wh (lo·lo dropped,
// ~2^-16 rel). 128x128 tile, 4 waves (2x2 of 64x64), 16x16x32 MFMA.
// A staged hi/lo in LDS [128][40] (pad 40: rows 80B, 16B-aligned, <=2-way).
// B fragments read directly from pre-transposed WT planes (L2-hot, no LDS).
// C/D layout (HW-verified): col = lane&15, row = (lane>>4)*4 + reg.
// OUTM: 0 -> f32 out; 1 -> bf16 out; 2 -> dual hi/lo bf16 planes.
// ---------------------------------------------------------------------------
template <int OUTM>
__global__ __launch_bounds__(256, 2) void gemm_mfma(
    const float* __restrict__ A, const bf16* __restrict__ WTh,
    const bf16* __restrict__ WTl, const float* __restrict__ bias,
    float* __restrict__ outF, bf16* __restrict__ outH, bf16* __restrict__ outL,
    int M, int mode, const int* __restrict__ segids,
    const float* __restrict__ segemb) {
  __shared__ __align__(16) bf16 Ah[128][40];
  __shared__ __align__(16) bf16 Al[128][40];

  int tid = threadIdx.x;
  int lane = tid & 63, w = tid >> 6;
  int wm = (w & 1) << 6, wn = (w >> 1) << 6;
  int lrow = lane & 15, lkb = (lane >> 4) << 3;
  int bn = blockIdx.x & 7, bm = blockIdx.x >> 3;  // bn-fast: W panels stay L2-hot
  int m0 = bm << 7, n0 = bn << 7;

  int sm = tid & 127, skb = (tid >> 7) << 4;

  f32x4 acc[4][4];
#pragma unroll
  for (int i = 0; i < 4; i++)
#pragma unroll
    for (int j = 0; j < 4; j++) {
      acc[i][j][0] = 0.f; acc[i][j][1] = 0.f;
      acc[i][j][2] = 0.f; acc[i][j][3] = 0.f;
    }

  for (int k0 = 0; k0 < 1024; k0 += 32) {
    {  // A stage: 16 f32 -> hi/lo bf16, 4x b128 LDS writes
      const float* asrc = A + (size_t)(m0 + sm) * 1024 + k0 + skb;
      float av16[16];
      *(f32x4*)&av16[0] = *(const f32x4*)asrc;
      *(f32x4*)&av16[4] = *(const f32x4*)(asrc + 4);
      *(f32x4*)&av16[8] = *(const f32x4*)(asrc + 8);
      *(f32x4*)&av16[12] = *(const f32x4*)(asrc + 12);
      union { bf16 b[16]; s16x8 v[2]; } hh, ll;
#pragma unroll
      for (int j = 0; j < 16; ++j) {
        float x = av16[j];
        bf16 hi = (bf16)x;
        hh.b[j] = hi;
        ll.b[j] = (bf16)(x - (float)hi);
      }
      *(s16x8*)&Ah[sm][skb] = hh.v[0];
      *(s16x8*)&Ah[sm][skb + 8] = hh.v[1];
      *(s16x8*)&Al[sm][skb] = ll.v[0];
      *(s16x8*)&Al[sm][skb + 8] = ll.v[1];
    }
    __syncthreads();

    s16x8 bh[4], bl[4];
#pragma unroll
    for (int nt = 0; nt < 4; ++nt) {
      size_t bro = (size_t)(n0 + wn + nt * 16 + lrow) * 1024 + k0 + lkb;
      bh[nt] = *(const s16x8*)&WTh[bro];
      bl[nt] = *(const s16x8*)&WTl[bro];
    }
    s16x8 ah[4], al[4];
#pragma unroll
    for (int mt = 0; mt < 4; ++mt) {
      ah[mt] = *(const s16x8*)&Ah[wm + mt * 16 + lrow][lkb];
      al[mt] = *(const s16x8*)&Al[wm + mt * 16 + lrow][lkb];
    }
#pragma unroll
    for (int mt = 0; mt < 4; ++mt)
#pragma unroll
      for (int nt = 0; nt < 4; ++nt) {
        acc[mt][nt] = __builtin_amdgcn_mfma_f32_16x16x32_bf16(
            ah[mt], bh[nt], acc[mt][nt], 0, 0, 0);
        acc[mt][nt] = __builtin_amdgcn_mfma_f32_16x16x32_bf16(
            ah[mt], bl[nt], acc[mt][nt], 0, 0, 0);
        acc[mt][nt] = __builtin_amdgcn_mfma_f32_16x16x32_bf16(
            al[mt], bh[nt], acc[mt][nt], 0, 0, 0);
      }
    __syncthreads();
  }

  int rbase = (lane >> 4) << 2;
#pragma unroll
  for (int mt = 0; mt < 4; ++mt) {
#pragma unroll
    for (int r = 0; r < 4; ++r) {
      int m = m0 + wm + mt * 16 + rbase + r;
      int seg = (mode == 1) ? segids[m] : 0;
#pragma unroll
      for (int nt = 0; nt < 4; ++nt) {
        int n = n0 + wn + nt * 16 + lrow;
        float v = acc[mt][nt][r] + bias[n];
        if (mode == 1) v += segemb[(size_t)seg * 1024 + n];
        size_t o = (size_t)m * 1024 + n;
        if constexpr (OUTM == 0) {
          outF[o] = v;
        } else if constexpr (OUTM == 1) {
          outH[o] = (bf16)v;
        } else {
          bf16 hi = (bf16)v;
          outH[o] = hi;
          outL[o] = (bf16)(v - (float)hi);
        }
      }
    }
  }
}

// ---------------------------------------------------------------------------
// qk_mfma: Sc[bg*TC + t-tBase][4096] = mask ? (Q[t].K[s])*0.125 : -1e9.
// Q,K given as hi/lo bf16 planes [row][1024]. 128t x 128s tile, K=64 = two
// 16x16x32 steps x3 passes. NO LDS: fragments straight from global (L2-hot
// per-(b,h) slices). bg = b*G+g, h = h0+g.
// ---------------------------------------------------------------------------
__global__ __launch_bounds__(256, 3) void qk_mfma(
    const bf16* __restrict__ Qh, const bf16* __restrict__ Ql,
    const bf16* __restrict__ Kh, const bf16* __restrict__ Kl,
    const int* __restrict__ mask, float* __restrict__ Sc,
    int G, int TC, int h0, int tBase) {
  int tid = threadIdx.x;
  int lane = tid & 63, w = tid >> 6;
  int wm = (w & 1) << 6, wn = (w >> 1) << 6;
  int lrow = lane & 15, lkb = (lane >> 4) << 3;
  int tiles_t = TC >> 7;
  int bid = blockIdx.x;
  int rest = bid % (tiles_t * 32);
  int bg = bid / (tiles_t * 32);
  int tm = rest % tiles_t, sn = rest / tiles_t;
  int b = bg / G, g = bg % G, h = h0 + g;
  int t0 = tBase + (tm << 7), s0 = sn << 7;
  int tl0 = t0 - tBase + bg * TC;

  f32x4 acc[4][4];
#pragma unroll
  for (int i = 0; i < 4; i++)
#pragma unroll
    for (int j = 0; j < 4; j++) {
      acc[i][j][0] = 0.f; acc[i][j][1] = 0.f;
      acc[i][j][2] = 0.f; acc[i][j][3] = 0.f;
    }

#pragma unroll
  for (int ks = 0; ks < 2; ++ks) {
    s16x8 ah[4], al[4], bh[4], bl[4];
#pragma unroll
    for (int mt = 0; mt < 4; ++mt) {
      size_t ro = (((size_t)((b << 9) + t0 + wm + mt * 16 + lrow)) << 10) +
                  (h << 6) + ks * 32 + lkb;
      ah[mt] = *(const s16x8*)&Qh[ro];
      al[mt] = *(const s16x8*)&Ql[ro];
    }
#pragma unroll
    for (int nt = 0; nt < 4; ++nt) {
      size_t ro = (((size_t)((b << 12) + s0 + wn + nt * 16 + lrow)) << 10) +
                  (h << 6) + ks * 32 + lkb;
      bh[nt] = *(const s16x8*)&Kh[ro];
      bl[nt] = *(const s16x8*)&Kl[ro];
    }
#pragma unroll
    for (int mt = 0; mt < 4; ++mt)
#pragma unroll
      for (int nt = 0; nt < 4; ++nt) {
        acc[mt][nt] = __builtin_amdgcn_mfma_f32_16x16x32_bf16(
            ah[mt], bh[nt], acc[mt][nt], 0, 0, 0);
        acc[mt][nt] = __builtin_amdgcn_mfma_f32_16x16x32_bf16(
            ah[mt], bl[nt], acc[mt][nt], 0, 0, 0);
        acc[mt][nt] = __builtin_amdgcn_mfma_f32_16x16x32_bf16(
            al[mt], bh[nt], acc[mt][nt], 0, 0, 0);
      }
  }

  const int* mrow = mask + (b << 12) + s0 + wn;
  bool mk[4];
#pragma unroll
  for (int nt = 0; nt < 4; ++nt) mk[nt] = (mrow[nt * 16 + lrow] != 0);

  int rbase = (lane >> 4) << 2;
#pragma unroll
  for (int mt = 0; mt < 4; ++mt) {
#pragma unroll
    for (int r = 0; r < 4; ++r) {
      size_t row = (((size_t)(tl0 + wm + mt * 16 + rbase + r)) << 12) + s0 + wn;
#pragma unroll
      for (int nt = 0; nt < 4; ++nt) {
        Sc[row + nt * 16 + lrow] =
            mk[nt] ? acc[mt][nt][r] * 0.125f : -1.0e9f;
      }
    }
  }
}

// ---------------------------------------------------------------------------
// Softmax (exact: max, __expf, sum) + provenance. All-register row.
// PMODE 0: normalized P -> Sc (f32, in place). PMODE 1: P -> Pb (bf16).
// ---------------------------------------------------------------------------
template <int PMODE>
__global__ __launch_bounds__(256, 2) void softmax_prov(
    float* __restrict__ Sc, bf16* __restrict__ Pb, float* __restrict__ prov,
    int G, int TC, int h0, int tBase) {
  __shared__ float red[4];

  int tid = threadIdx.x, wv = tid >> 6;
  int bid = blockIdx.x;
  int b = bid / TC, tl = bid % TC;
  int t = tBase + tl;

  float pacc[16];
#pragma unroll
  for (int i = 0; i < 16; i++) pacc[i] = 0.f;

  for (int g = 0; g < G; ++g) {
    size_t base = ((size_t)((b * G + g) * TC + tl)) << 12;
    f32x4 v[4];
    float mx = -3.0e38f;
#pragma unroll
    for (int it = 0; it < 4; ++it) {
      int s = (tid << 2) + (it << 10);
      v[it] = *(const f32x4*)&Sc[base + s];
      mx = fmaxf(fmaxf(fmaxf(mx, v[it][0]), v[it][1]), fmaxf(v[it][2], v[it][3]));
    }
#pragma unroll
    for (int o = 32; o; o >>= 1) mx = fmaxf(mx, __shfl_xor(mx, o));
    if ((tid & 63) == 0) red[wv] = mx;
    __syncthreads();
    float m = fmaxf(fmaxf(red[0], red[1]), fmaxf(red[2], red[3]));
    __syncthreads();

    float sm = 0.f;
#pragma unroll
    for (int it = 0; it < 4; ++it) {
      f32x4 p;
      p[0] = __expf(v[it][0] - m);
      p[1] = __expf(v[it][1] - m);
      p[2] = __expf(v[it][2] - m);
      p[3] = __expf(v[it][3] - m);
      v[it] = p;
      sm += (p[0] + p[1]) + (p[2] + p[3]);
    }
#pragma unroll
    for (int o = 32; o; o >>= 1) sm += __shfl_xor(sm, o);
    if ((tid & 63) == 0) red[wv] = sm;
    __syncthreads();
    float il = 1.0f / (((red[0] + red[1]) + (red[2] + red[3])));
    __syncthreads();

#pragma unroll
    for (int it = 0; it < 4; ++it) {
      int s = (tid << 2) + (it << 10);
      f32x4 pn;
      pn[0] = v[it][0] * il;
      pn[1] = v[it][1] * il;
      pn[2] = v[it][2] * il;
      pn[3] = v[it][3] * il;
      if constexpr (PMODE == 1) {
        bf16x4 pb;
        pb[0] = (bf16)pn[0]; pb[1] = (bf16)pn[1];
        pb[2] = (bf16)pn[2]; pb[3] = (bf16)pn[3];
        *(bf16x4*)&Pb[base + s] = pb;
      } else {
        *(f32x4*)&Sc[base + s] = pn;
      }
      pacc[it * 4 + 0] += pn[0] * 0.0625f;
      pacc[it * 4 + 1] += pn[1] * 0.0625f;
      pacc[it * 4 + 2] += pn[2] * 0.0625f;
      pacc[it * 4 + 3] += pn[3] * 0.0625f;
    }
  }

  size_t pbase = (((size_t)((b << 9) + t)) << 12);
#pragma unroll
  for (int it = 0; it < 4; ++it) {
    int s = (tid << 2) + (it << 10);
    f32x4 pa;
    pa[0] = pacc[it * 4 + 0]; pa[1] = pacc[it * 4 + 1];
    pa[2] = pacc[it * 4 + 2]; pa[3] = pacc[it * 4 + 3];
    if (h0 != 0) {
      f32x4 old = *(const f32x4*)&prov[pbase + s];
      pa[0] += old[0]; pa[1] += old[1]; pa[2] += old[2]; pa[3] += old[3];
    }
    *(f32x4*)&prov[pbase + s] = pa;
  }
}

// ---------------------------------------------------------------------------
// PV (f32 VALU core, unchanged from verified round-3 version).
// ---------------------------------------------------------------------------
template <typename PT, typename VT>
__global__ __launch_bounds__(256, 2) void pv_gemm(
    const PT* __restrict__ P, const VT* __restrict__ Vp,
    float* __restrict__ Oat, int G, int TC, int h0, int tBase) {
  __shared__ __align__(16) float PsT[32][68];
  __shared__ __align__(16) float Vs[32][68];

  int tid = threadIdx.x, tx = tid & 15, ty = tid >> 4;
  int ntt = TC >> 6;
  int bid = blockIdx.x;
  int tt = bid % ntt, bg = bid / ntt;
  int b = bg / G, g = bg % G, h = h0 + g;
  int tl0 = tt << 6;

  int st = tid & 63, sc = (tid >> 6) * 8;
  int vr = tid >> 3, vc = (tid & 7) * 8;

  float acc[4][4];
#pragma unroll
  for (int i = 0; i < 4; i++)
#pragma unroll
    for (int j = 0; j < 4; j++) acc[i][j] = 0.f;

  for (int k0 = 0; k0 < 4096; k0 += 32) {
    {
      const PT* src = P + (((size_t)(bg * TC + tl0 + st)) << 12) + k0 + sc;
      if constexpr (sizeof(PT) == 2) {
        bf16x8 p8 = *(const bf16x8*)src;
#pragma unroll
        for (int j = 0; j < 8; j++) PsT[sc + j][st] = (float)p8[j];
      } else {
        f32x4 p0 = *(const f32x4*)src;
        f32x4 p1 = *(const f32x4*)(src + 4);
#pragma unroll
        for (int j = 0; j < 4; j++) {
          PsT[sc + j][st] = p0[j];
          PsT[sc + 4 + j][st] = p1[j];
        }
      }
    }
    {
      const VT* src = Vp + (((size_t)((b << 12) + k0 + vr)) << 10) + (h << 6) + vc;
      if constexpr (sizeof(VT) == 4) {
        *(f32x4*)&Vs[vr][vc] = *(const f32x4*)src;
        *(f32x4*)&Vs[vr][vc + 4] = *(const f32x4*)(src + 4);
      } else {
        bf16x8 v8 = *(const bf16x8*)src;
#pragma unroll
        for (int j = 0; j < 8; j++) Vs[vr][vc + j] = (float)v8[j];
      }
    }
    __syncthreads();
#pragma unroll
    for (int kk = 0; kk < 32; ++kk) {
      f32x4 av = *(const f32x4*)&PsT[kk][ty * 4];
      f32x4 bv = *(const f32x4*)&Vs[kk][tx * 4];
#pragma unroll
      for (int i = 0; i < 4; i++)
#pragma unroll
        for (int j = 0; j < 4; j++) acc[i][j] += av[i] * bv[j];
    }
    __syncthreads();
  }

#pragma unroll
  for (int i = 0; i < 4; i++) {
    int t = tBase + tl0 + ty * 4 + i;
    f32x4 v;
#pragma unroll
    for (int j = 0; j < 4; j++) v[j] = acc[i][j];
    *(f32x4*)&Oat[(((size_t)((b << 9) + t)) << 10) + (h << 6) + (tx << 2)] = v;
  }
}

// ---------------------------------------------------------------------------
// Fallback GEMM (f32 VALU, verified) + naive attention — only if ws tiny.
// ---------------------------------------------------------------------------
template <typename OUT>
__global__ __launch_bounds__(256, 2) void gemm_f32(
    const float* __restrict__ A, const float* __restrict__ W,
    const float* __restrict__ bias, OUT* __restrict__ out, int M, int mode,
    const int* __restrict__ segids, const float* __restrict__ segemb) {
  __shared__ __align__(16) float AsT[32][132];
  __shared__ __align__(16) float Bs[32][132];

  int tid = threadIdx.x;
  int tx = tid & 15, ty = tid >> 4;
  int nTilesM = M >> 7;
  int bm = blockIdx.x % nTilesM, bn = blockIdx.x / nTilesM;
  int m0 = bm * 128, n0 = bn * 128;

  int sm = tid & 127;
  int skb = (tid >> 7) * 16;

  float acc[8][8];
#pragma unroll
  for (int i = 0; i < 8; i++)
#pragma unroll
    for (int j = 0; j < 8; j++) acc[i][j] = 0.f;

  for (int k0 = 0; k0 < 1024; k0 += 32) {
    {
      const float* src = A + (size_t)(m0 + sm) * 1024 + k0 + skb;
      f32x4 a0 = *(const f32x4*)src;
      f32x4 a1 = *(const f32x4*)(src + 4);
      f32x4 a2 = *(const f32x4*)(src + 8);
      f32x4 a3 = *(const f32x4*)(src + 12);
#pragma unroll
      for (int j = 0; j < 4; j++) {
        AsT[skb + j][sm] = a0[j];
        AsT[skb + 4 + j][sm] = a1[j];
        AsT[skb + 8 + j][sm] = a2[j];
        AsT[skb + 12 + j][sm] = a3[j];
      }
    }
#pragma unroll
    for (int u = tid; u < 512; u += 256) {
      int r = u >> 4, cc = (u & 15) * 8;
      const float* src = W + (size_t)(k0 + r) * 1024 + n0 + cc;
      *(f32x4*)&Bs[r][cc] = *(const f32x4*)src;
      *(f32x4*)&Bs[r][cc + 4] = *(const f32x4*)(src + 4);
    }
    __syncthreads();
#pragma unroll
    for (int kk = 0; kk < 32; kk++) {
      f32x4 av0 = *(const f32x4*)&AsT[kk][ty * 8];
      f32x4 av1 = *(const f32x4*)&AsT[kk][ty * 8 + 4];
      f32x4 bv0 = *(const f32x4*)&Bs[kk][tx * 4];
      f32x4 bv1 = *(const f32x4*)&Bs[kk][64 + tx * 4];
      float av[8] = {av0[0], av0[1], av0[2], av0[3],
                     av1[0], av1[1], av1[2], av1[3]};
#pragma unroll
      for (int i = 0; i < 8; i++) {
#pragma unroll
        for (int j = 0; j < 4; j++) {
          acc[i][j] += av[i] * bv0[j];
          acc[i][4 + j] += av[i] * bv1[j];
        }
      }
    }
    __syncthreads();
  }

#pragma unroll
  for (int i = 0; i < 8; i++) {
    int m = m0 + ty * 8 + i;
    int seg = (mode == 1) ? segids[m] : 0;
#pragma unroll
    for (int jh = 0; jh < 2; jh++) {
#pragma unroll
      for (int j = 0; j < 4; j++) {
        int n = n0 + jh * 64 + tx * 4 + j;
        float v = acc[i][jh * 4 + j] + bias[n];
        if (mode == 1) v += segemb[(size_t)seg * 1024 + n];
        out[(size_t)m * 1024 + n] = (OUT)v;
      }
    }
  }
}

__global__ __launch_bounds__(256) void attn_naive(
    const float* __restrict__ Qp, const float* __restrict__ Kp,
    const bf16* __restrict__ Vp, const int* __restrict__ mask,
    float* __restrict__ Oatt, float* __restrict__ prov) {
  int bt = blockIdx.x;
  int b = bt >> 9, t = bt & 511;
  __shared__ float qs[64];
  __shared__ float sc[4096];
  __shared__ float pacc[4096];
  __shared__ float red[256];
  __shared__ float po[4][64];
  int tid = threadIdx.x, wv = tid >> 6, lane = tid & 63;

  for (int s = tid; s < 4096; s += 256) pacc[s] = 0.f;
  const int* mrow = mask + (b << 12);

  for (int h = 0; h < 16; ++h) {
    __syncthreads();
    if (tid < 64) qs[tid] = Qp[((size_t)(b * 512 + t)) * 1024 + h * 64 + tid];
    __syncthreads();
    for (int s = tid; s < 4096; s += 256) {
      const float* krow = Kp + ((size_t)((b << 12) + s)) * 1024 + h * 64;
      float d = 0.f;
#pragma unroll
      for (int kk = 0; kk < 64; kk += 4) {
        f32x4 kv = *(const f32x4*)(krow + kk);
#pragma unroll
        for (int j = 0; j < 4; ++j) d += qs[kk + j] * kv[j];
      }
      sc[s] = (mrow[s] != 0) ? d * 0.125f : -1.0e9f;
    }
    __syncthreads();
    float mx = -3.0e38f;
    for (int s = tid; s < 4096; s += 256) mx = fmaxf(mx, sc[s]);
    red[tid] = mx;
    __syncthreads();
    for (int off = 128; off; off >>= 1) {
      if (tid < off) red[tid] = fmaxf(red[tid], red[tid + off]);
      __syncthreads();
    }
    float m = red[0];
    __syncthreads();
    float sm = 0.f;
    for (int s = tid; s < 4096; s += 256) {
      float p = __expf(sc[s] - m);
      sc[s] = p;
      sm += p;
    }
    red[tid] = sm;
    __syncthreads();
    for (int off = 128; off; off >>= 1) {
      if (tid < off) red[tid] += red[tid + off];
      __syncthreads();
    }
    float il = 1.0f / red[0];
    for (int s = tid; s < 4096; s += 256) pacc[s] += sc[s] * il * 0.0625f;
    float o = 0.f;
    const bf16* vb = Vp + ((size_t)((b << 12) + wv * 1024)) * 1024 + h * 64 + lane;
    for (int s = 0; s < 1024; ++s) o += sc[wv * 1024 + s] * (float)vb[(size_t)s * 1024];
    po[wv][lane] = o;
    __syncthreads();
    if (tid < 64) {
      float oo = (po[0][tid] + po[1][tid] + po[2][tid] + po[3][tid]) * il;
      Oatt[((size_t)(b * 512 + t)) * 1024 + h * 64 + tid] = oo;
    }
  }
  __syncthreads();
  for (int s = tid; s < 4096; s += 256)
    prov[((size_t)(b * 512 + t)) * 4096 + s] = pacc[s];
}

// ---------------------------------------------------------------------------
extern "C" void kernel_launch(void* const* d_in, const int* in_sizes, int n_in,
                              void* d_out, int out_size, void* d_ws, size_t ws_size,
                              hipStream_t stream) {
  const float* query = (const float*)d_in[0];
  const float* key = (const float*)d_in[1];
  const float* value = (const float*)d_in[2];
  const int* amask = (const int*)d_in[3];
  const int* segid = (const int*)d_in[4];
  const float* Wq = (const float*)d_in[5];
  const float* bq = (const float*)d_in[6];
  const float* Wk = (const float*)d_in[7];
  const float* bk = (const float*)d_in[8];
  const float* Wv = (const float*)d_in[9];
  const float* bv = (const float*)d_in[10];
  const float* Wo = (const float*)d_in[11];
  const float* bo = (const float*)d_in[12];
  const float* semb = (const float*)d_in[13];

  char* ws = (char*)d_ws;
  float* outAtt = (float*)d_out;                  // [4,512,1024] f32
  float* outProv = outAtt + (size_t)2048 * 1024;  // [4,512,4096] f32

  const size_t MB = 1ull << 20;
  static const int cand[7][2] = {{16, 512}, {8, 512}, {4, 512}, {2, 512},
                                 {1, 512},  {1, 256}, {1, 128}};
  int G = 0, TC = 0;
  size_t scBytes = 0;
  for (int ci = 0; ci < 7; ++ci) {
    size_t sb = (size_t)4 * cand[ci][0] * cand[ci][1] * 4096 * 4;
    if (112 * MB + sb <= ws_size) { G = cand[ci][0]; TC = cand[ci][1]; scBytes = sb; break; }
  }

  if (G > 0) {
    bool vf32 = (144 * MB + scBytes <= ws_size);
    size_t scOff = (vf32 ? 144 : 112) * MB;
    bool usePb = (scOff + scBytes + scBytes / 2 <= ws_size);

    bf16* Qh = (bf16*)ws;                      // 4 MB [2048,1024]
    bf16* Ql = (bf16*)(ws + 4 * MB);           // 4 MB
    bf16* Kh = (bf16*)(ws + 8 * MB);           // 32 MB [16384,1024]
    bf16* Kl = (bf16*)(ws + 40 * MB);          // 32 MB
    float* Vpf = (float*)(ws + 72 * MB);       // 64 MB f32 (or 32 MB bf16)
    bf16* Vpb = (bf16*)(ws + 72 * MB);
    float* OatF = (float*)(ws + (vf32 ? 136 : 104) * MB);  // 8 MB
    float* Sc = (float*)(ws + scOff);
    bf16* Pb = (bf16*)(ws + scOff + scBytes);
    // WT scratch lives in the Sc region (dead during projections / O-proj)
    bf16* WTh = (bf16*)(ws + scOff);
    bf16* WTl = WTh + (size_t)1024 * 1024;

    wtrans<<<256, 256, 0, stream>>>(Wq, WTh, WTl);
    gemm_mfma<2><<<8 * 16, 256, 0, stream>>>(query, WTh, WTl, bq, nullptr, Qh,
                                             Ql, 2048, 0, nullptr, nullptr);
    wtrans<<<256, 256, 0, stream>>>(Wk, WTh, WTl);
    gemm_mfma<2><<<8 * 128, 256, 0, stream>>>(key, WTh, WTl, bk, nullptr, Kh,
                                              Kl, 16384, 1, segid, semb);
    wtrans<<<256, 256, 0, stream>>>(Wv, WTh, WTl);
    if (vf32)
      gemm_mfma<0><<<8 * 128, 256, 0, stream>>>(value, WTh, WTl, bv, Vpf,
                                                nullptr, nullptr, 16384, 0,
                                                nullptr, nullptr);
    else
      gemm_mfma<1><<<8 * 128, 256, 0, stream>>>(value, WTh, WTl, bv, nullptr,
                                                Vpb, nullptr, 16384, 0,
                                                nullptr, nullptr);

    int nHC = 16 / G, nTCk = 512 / TC;
    for (int hc = 0; hc < nHC; ++hc) {
      int h0 = hc * G;
      for (int tc = 0; tc < nTCk; ++tc) {
        int tBase = tc * TC;
        qk_mfma<<<4 * G * (TC >> 7) * 32, 256, 0, stream>>>(
            Qh, Ql, Kh, Kl, amask, Sc, G, TC, h0, tBase);
        if (usePb)
          softmax_prov<1><<<4 * TC, 256, 0, stream>>>(Sc, Pb, outProv, G, TC, h0, tBase);
        else
          softmax_prov<0><<<4 * TC, 256, 0, stream>>>(Sc, Pb, outProv, G, TC, h0, tBase);
        int pvGrid = 4 * G * (TC >> 6);
        if (usePb) {
          if (vf32)
            pv_gemm<bf16, float><<<pvGrid, 256, 0, stream>>>(Pb, Vpf, OatF, G, TC, h0, tBase);
          else
            pv_gemm<bf16, bf16><<<pvGrid, 256, 0, stream>>>(Pb, Vpb, OatF, G, TC, h0, tBase);
        } else {
          if (vf32)
            pv_gemm<float, float><<<pvGrid, 256, 0, stream>>>(Sc, Vpf, OatF, G, TC, h0, tBase);
          else
            pv_gemm<float, bf16><<<pvGrid, 256, 0, stream>>>(Sc, Vpb, OatF, G, TC, h0, tBase);
        }
      }
    }
    wtrans<<<256, 256, 0, stream>>>(Wo, WTh, WTl);
    gemm_mfma<0><<<8 * 16, 256, 0, stream>>>(OatF, WTh, WTl, bo, outAtt,
                                             nullptr, nullptr, 2048, 0,
                                             nullptr, nullptr);
  } else {
    // Fallback: original verified path (needs 112 MB).
    float* Qp = (float*)ws;                   // 8 MB
    float* Kp = (float*)(ws + 8 * MB);        // 64 MB
    bf16* Vp = (bf16*)(ws + 72 * MB);         // 32 MB
    float* OatF = (float*)(ws + 104 * MB);    // 8 MB

    gemm_f32<float><<<16 * 8, 256, 0, stream>>>(query, Wq, bq, Qp, 2048, 0, nullptr, nullptr);
    gemm_f32<float><<<128 * 8, 256, 0, stream>>>(key, Wk, bk, Kp, 16384, 1, segid, semb);
    gemm_f32<bf16><<<128 * 8, 256, 0, stream>>>(value, Wv, bv, Vp, 16384, 0, nullptr, nullptr);
    attn_naive<<<2048, 256, 0, stream>>>(Qp, Kp, Vp, amask, OatF, outProv);
    gemm_f32<float><<<16 * 8, 256, 0, stream>>>(OatF, Wo, bo, outAtt, 2048, 0, nullptr, nullptr);
  }
}